// Round 2
// baseline (80.945 us; speedup 1.0000x reference)
//
#include <hip/hip_runtime.h>

#define NB 524288
#define NC 32
#define EPSV 1e-4f
#define DTB 0.12f      // DT * BETA
#define CLAMPV 3.0f
#define NSTEPS 4

__global__ __launch_bounds__(256, 4) void pm_kernel(
    const float* __restrict__ z_in,
    const float* __restrict__ centers,
    const float* __restrict__ mus,
    float* __restrict__ out)
{
    const int i = blockIdx.x * 256 + threadIdx.x;
    const float4* zp = (const float4*)z_in;
    float4 a = zp[(size_t)i * 2];
    float4 b = zp[(size_t)i * 2 + 1];
    float z[8] = {a.x, a.y, a.z, a.w, b.x, b.y, b.z, b.w};

    #pragma unroll 1
    for (int s = 0; s < NSTEPS; ++s) {
        float n = 1.0f;
        float g[8] = {0.f, 0.f, 0.f, 0.f, 0.f, 0.f, 0.f, 0.f};
        #pragma unroll
        for (int c = 0; c < NC; ++c) {
            // Uniform-address reads: compiler promotes to s_load (SGPRs,
            // scalar cache) -> no LDS, no VGPR cost for center data.
            float rv[8];
            #pragma unroll
            for (int d = 0; d < 8; ++d) rv[d] = z[d] - centers[c * 8 + d];

            // Two independent FMA chains -> half the r2 latency depth.
            float r2a = fmaf(rv[0], rv[0], EPSV);
            r2a = fmaf(rv[1], rv[1], r2a);
            r2a = fmaf(rv[2], rv[2], r2a);
            r2a = fmaf(rv[3], rv[3], r2a);
            float r2b = rv[4] * rv[4];
            r2b = fmaf(rv[5], rv[5], r2b);
            r2b = fmaf(rv[6], rv[6], r2b);
            r2b = fmaf(rv[7], rv[7], r2b);
            float r2 = r2a + r2b;

            float rinv = rsqrtf(r2);          // v_rsq_f32
            float w    = mus[c] * rinv;       // mu / r
            n += w;
            float w3   = (w * rinv) * rinv;   // mu / (r * r2)
            #pragma unroll
            for (int d = 0; d < 8; ++d) g[d] = fmaf(-w3, rv[d], g[d]);
        }
        float scale = DTB / n;                // one real divide per step
        #pragma unroll
        for (int d = 0; d < 8; ++d) {
            float zn = fmaf(scale, g[d], z[d]);
            z[d] = fminf(fmaxf(zn, -CLAMPV), CLAMPV);
        }
    }

    float4 o0 = {z[0], z[1], z[2], z[3]};
    float4 o1 = {z[4], z[5], z[6], z[7]};
    float4* op = (float4*)out;
    op[(size_t)i * 2]     = o0;
    op[(size_t)i * 2 + 1] = o1;
}

extern "C" void kernel_launch(void* const* d_in, const int* in_sizes, int n_in,
                              void* d_out, int out_size, void* d_ws, size_t ws_size,
                              hipStream_t stream) {
    const float* z       = (const float*)d_in[0];
    const float* centers = (const float*)d_in[1];
    const float* mus     = (const float*)d_in[2];
    float* out           = (float*)d_out;

    dim3 block(256);
    dim3 grid(NB / 256);   // 2048 blocks
    pm_kernel<<<grid, block, 0, stream>>>(z, centers, mus, out);
}

// Round 3
// 74.229 us; speedup vs baseline: 1.0905x; 1.0905x over previous
//
#include <hip/hip_runtime.h>

#define NB 524288
#define NC 32
#define EPSV 1e-4f
#define DTB 0.12f      // DT * BETA
#define CLAMPV 3.0f
#define NSTEPS 4

__global__ __launch_bounds__(256, 4) void pm_kernel(
    const float* __restrict__ z_in,
    const float* __restrict__ centers,
    const float* __restrict__ mus,
    float* __restrict__ out)
{
    const int i = blockIdx.x * 256 + threadIdx.x;
    const float4* zp = (const float4*)z_in;
    float4 a = zp[(size_t)i * 2];
    float4 b = zp[(size_t)i * 2 + 1];
    float z[8] = {a.x, a.y, a.z, a.w, b.x, b.y, b.z, b.w};

    #pragma unroll 1
    for (int s = 0; s < NSTEPS; ++s) {
        float n = 1.0f;
        float g[8] = {0.f, 0.f, 0.f, 0.f, 0.f, 0.f, 0.f, 0.f};
        #pragma unroll
        for (int c = 0; c < NC; ++c) {
            // Uniform-address reads -> s_load into SGPRs (scalar cache).
            float rv[8];
            #pragma unroll
            for (int d = 0; d < 8; ++d) rv[d] = z[d] - centers[c * 8 + d];

            // Two independent FMA chains -> half the r2 latency depth.
            float r2a = fmaf(rv[0], rv[0], EPSV);
            r2a = fmaf(rv[1], rv[1], r2a);
            r2a = fmaf(rv[2], rv[2], r2a);
            r2a = fmaf(rv[3], rv[3], r2a);
            float r2b = rv[4] * rv[4];
            r2b = fmaf(rv[5], rv[5], r2b);
            r2b = fmaf(rv[6], rv[6], r2b);
            r2b = fmaf(rv[7], rv[7], r2b);
            float r2 = r2a + r2b;

            // Raw HW v_rsq_f32 (~1 ulp) -- avoids the IEEE sqrt+div expansion.
            float rinv = __builtin_amdgcn_rsqf(r2);
            float w    = mus[c] * rinv;       // mu / r
            n += w;
            float w3   = (w * rinv) * rinv;   // mu / (r * r2)
            #pragma unroll
            for (int d = 0; d < 8; ++d) g[d] = fmaf(-w3, rv[d], g[d]);
        }
        // Raw HW v_rcp_f32 instead of the full-precision divide sequence.
        float scale = DTB * __builtin_amdgcn_rcpf(n);
        #pragma unroll
        for (int d = 0; d < 8; ++d) {
            float zn = fmaf(scale, g[d], z[d]);
            z[d] = fminf(fmaxf(zn, -CLAMPV), CLAMPV);
        }
    }

    float4 o0 = {z[0], z[1], z[2], z[3]};
    float4 o1 = {z[4], z[5], z[6], z[7]};
    float4* op = (float4*)out;
    op[(size_t)i * 2]     = o0;
    op[(size_t)i * 2 + 1] = o1;
}

extern "C" void kernel_launch(void* const* d_in, const int* in_sizes, int n_in,
                              void* d_out, int out_size, void* d_ws, size_t ws_size,
                              hipStream_t stream) {
    const float* z       = (const float*)d_in[0];
    const float* centers = (const float*)d_in[1];
    const float* mus     = (const float*)d_in[2];
    float* out           = (float*)d_out;

    dim3 block(256);
    dim3 grid(NB / 256);   // 2048 blocks
    pm_kernel<<<grid, block, 0, stream>>>(z, centers, mus, out);
}

// Round 4
// 55.148 us; speedup vs baseline: 1.4678x; 1.3460x over previous
//
#include <hip/hip_runtime.h>

#define NB 524288
#define NC 32
#define EPSV 1e-4f
#define DTB 0.12f      // DT * BETA
#define CLAMPV 3.0f
#define NSTEPS 4

typedef float f32x2 __attribute__((ext_vector_type(2)));

__global__ __launch_bounds__(256, 4) void pm_kernel(
    const float* __restrict__ z_in,
    const float* __restrict__ centers,
    const float* __restrict__ mus,
    float* __restrict__ out)
{
    const int i = blockIdx.x * 256 + threadIdx.x;
    const float4* zp = (const float4*)z_in;
    float4 a = zp[(size_t)i * 2];
    float4 b = zp[(size_t)i * 2 + 1];
    f32x2 z0 = {a.x, a.y}, z1 = {a.z, a.w}, z2 = {b.x, b.y}, z3 = {b.z, b.w};

    // Wave-uniform center reads -> s_load into SGPR pairs (VOP3P-legal srcs).
    const f32x2* cp = (const f32x2*)centers;

    #pragma unroll 1
    for (int s = 0; s < NSTEPS; ++s) {
        float n = 1.0f;
        f32x2 g0 = {0.f, 0.f}, g1 = {0.f, 0.f}, g2 = {0.f, 0.f}, g3 = {0.f, 0.f};
        const f32x2 eps2 = {EPSV, 0.0f};
        #pragma unroll
        for (int c = 0; c < NC; ++c) {
            // v_pk_add_f32 (sub via neg modifier)
            f32x2 r0 = z0 - cp[c * 4 + 0];
            f32x2 r1 = z1 - cp[c * 4 + 1];
            f32x2 r2v = z2 - cp[c * 4 + 2];
            f32x2 r3 = z3 - cp[c * 4 + 3];

            // packed dot-product chain, EPS seeded into lane 0
            f32x2 p = __builtin_elementwise_fma(r0, r0, eps2);
            p = __builtin_elementwise_fma(r1, r1, p);
            p = __builtin_elementwise_fma(r2v, r2v, p);
            p = __builtin_elementwise_fma(r3, r3, p);
            float d2 = p.x + p.y;

            float rinv = __builtin_amdgcn_rsqf(d2);   // v_rsq_f32
            float w    = mus[c] * rinv;               // mu / r
            n += w;
            float w3   = (w * rinv) * rinv;           // mu / (r * r2)
            f32x2 nw3  = {-w3, -w3};                  // neg folds into VOP3P
            g0 = __builtin_elementwise_fma(nw3, r0, g0);
            g1 = __builtin_elementwise_fma(nw3, r1, g1);
            g2 = __builtin_elementwise_fma(nw3, r2v, g2);
            g3 = __builtin_elementwise_fma(nw3, r3, g3);
        }
        float scale = DTB * __builtin_amdgcn_rcpf(n); // v_rcp_f32
        f32x2 sv = {scale, scale};
        z0 = __builtin_elementwise_fma(sv, g0, z0);
        z1 = __builtin_elementwise_fma(sv, g1, z1);
        z2 = __builtin_elementwise_fma(sv, g2, z2);
        z3 = __builtin_elementwise_fma(sv, g3, z3);
        const f32x2 lo = {-CLAMPV, -CLAMPV}, hi = {CLAMPV, CLAMPV};
        z0 = __builtin_elementwise_min(__builtin_elementwise_max(z0, lo), hi);
        z1 = __builtin_elementwise_min(__builtin_elementwise_max(z1, lo), hi);
        z2 = __builtin_elementwise_min(__builtin_elementwise_max(z2, lo), hi);
        z3 = __builtin_elementwise_min(__builtin_elementwise_max(z3, lo), hi);
    }

    float4 o0 = {z0.x, z0.y, z1.x, z1.y};
    float4 o1 = {z2.x, z2.y, z3.x, z3.y};
    float4* op = (float4*)out;
    op[(size_t)i * 2]     = o0;
    op[(size_t)i * 2 + 1] = o1;
}

extern "C" void kernel_launch(void* const* d_in, const int* in_sizes, int n_in,
                              void* d_out, int out_size, void* d_ws, size_t ws_size,
                              hipStream_t stream) {
    const float* z       = (const float*)d_in[0];
    const float* centers = (const float*)d_in[1];
    const float* mus     = (const float*)d_in[2];
    float* out           = (float*)d_out;

    dim3 block(256);
    dim3 grid(NB / 256);   // 2048 blocks
    pm_kernel<<<grid, block, 0, stream>>>(z, centers, mus, out);
}

// Round 5
// 49.589 us; speedup vs baseline: 1.6323x; 1.1121x over previous
//
#include <hip/hip_runtime.h>

#define NB 524288
#define NC 32
#define EPSV 1e-4f
#define DTB 0.12f      // DT * BETA
#define CLAMPV 3.0f
#define NSTEPS 4

typedef float f32x2 __attribute__((ext_vector_type(2)));

__device__ __forceinline__ f32x2 pk_fma(f32x2 a, f32x2 b, f32x2 c) {
    return __builtin_elementwise_fma(a, b, c);
}

__global__ __launch_bounds__(256, 4) void pm_kernel(
    const float* __restrict__ z_in,
    const float* __restrict__ centers,
    const float* __restrict__ mus,
    float* __restrict__ out)
{
    const int tid = blockIdx.x * 256 + threadIdx.x;
    const int ia = tid;              // point a
    const int ib = tid + NB / 2;     // point b (coalesced second half)

    const float4* zp = (const float4*)z_in;
    float4 a0 = zp[(size_t)ia * 2], a1 = zp[(size_t)ia * 2 + 1];
    float4 b0 = zp[(size_t)ib * 2], b1 = zp[(size_t)ib * 2 + 1];
    f32x2 za[4] = {{a0.x, a0.y}, {a0.z, a0.w}, {a1.x, a1.y}, {a1.z, a1.w}};
    f32x2 zb[4] = {{b0.x, b0.y}, {b0.z, b0.w}, {b1.x, b1.y}, {b1.z, b1.w}};

    // Wave-uniform center reads -> s_load into SGPR pairs.
    const f32x2* cp = (const f32x2*)centers;

    // bb[c] = |c|^2 + EPS  (wave-uniform, lives in VGPRs, static indexing)
    float bb[NC];
    #pragma unroll
    for (int c = 0; c < NC; ++c) {
        f32x2 q = cp[c * 4 + 0] * cp[c * 4 + 0];
        q = pk_fma(cp[c * 4 + 1], cp[c * 4 + 1], q);
        q = pk_fma(cp[c * 4 + 2], cp[c * 4 + 2], q);
        q = pk_fma(cp[c * 4 + 3], cp[c * 4 + 3], q);
        bb[c] = q.x + q.y + EPSV;
    }

    #pragma unroll 1
    for (int s = 0; s < NSTEPS; ++s) {
        // zz = |z|^2 per point
        f32x2 qa = za[0] * za[0];
        qa = pk_fma(za[1], za[1], qa);
        qa = pk_fma(za[2], za[2], qa);
        qa = pk_fma(za[3], za[3], qa);
        float zza = qa.x + qa.y;
        f32x2 qb = zb[0] * zb[0];
        qb = pk_fma(zb[1], zb[1], qb);
        qb = pk_fma(zb[2], zb[2], qb);
        qb = pk_fma(zb[3], zb[3], qb);
        float zzb = qb.x + qb.y;

        float na = 1.0f, nb = 1.0f;
        float swa = 0.0f, swb = 0.0f;
        f32x2 gca[4] = {{0.f,0.f},{0.f,0.f},{0.f,0.f},{0.f,0.f}};
        f32x2 gcb[4] = {{0.f,0.f},{0.f,0.f},{0.f,0.f},{0.f,0.f}};

        #pragma unroll
        for (int c = 0; c < NC; ++c) {
            const f32x2 c0 = cp[c * 4 + 0], c1 = cp[c * 4 + 1];
            const f32x2 c2 = cp[c * 4 + 2], c3 = cp[c * 4 + 3];
            const float mu = mus[c];
            const float base = bb[c];

            // point a
            f32x2 pa = za[0] * c0;
            pa = pk_fma(za[1], c1, pa);
            pa = pk_fma(za[2], c2, pa);
            pa = pk_fma(za[3], c3, pa);
            float dota = pa.x + pa.y;
            float r2a = fmaf(-2.0f, dota, zza + base);
            float rinva = __builtin_amdgcn_rsqf(r2a);
            float wa = mu * rinva;
            na += wa;
            float w3a = (wa * rinva) * rinva;
            swa += w3a;
            f32x2 w3av = {w3a, w3a};
            gca[0] = pk_fma(w3av, c0, gca[0]);
            gca[1] = pk_fma(w3av, c1, gca[1]);
            gca[2] = pk_fma(w3av, c2, gca[2]);
            gca[3] = pk_fma(w3av, c3, gca[3]);

            // point b
            f32x2 pb = zb[0] * c0;
            pb = pk_fma(zb[1], c1, pb);
            pb = pk_fma(zb[2], c2, pb);
            pb = pk_fma(zb[3], c3, pb);
            float dotb = pb.x + pb.y;
            float r2b = fmaf(-2.0f, dotb, zzb + base);
            float rinvb = __builtin_amdgcn_rsqf(r2b);
            float wb = mu * rinvb;
            nb += wb;
            float w3b = (wb * rinvb) * rinvb;
            swb += w3b;
            f32x2 w3bv = {w3b, w3b};
            gcb[0] = pk_fma(w3bv, c0, gcb[0]);
            gcb[1] = pk_fma(w3bv, c1, gcb[1]);
            gcb[2] = pk_fma(w3bv, c2, gcb[2]);
            gcb[3] = pk_fma(w3bv, c3, gcb[3]);
        }

        // g = gc - sw3 * z ;  z = clamp(z + scale * g)
        float sca = DTB * __builtin_amdgcn_rcpf(na);
        float scb = DTB * __builtin_amdgcn_rcpf(nb);
        f32x2 nswa = {-swa, -swa}, nswb = {-swb, -swb};
        f32x2 scav = {sca, sca},   scbv = {scb, scb};
        const f32x2 lo = {-CLAMPV, -CLAMPV}, hi = {CLAMPV, CLAMPV};
        #pragma unroll
        for (int k = 0; k < 4; ++k) {
            f32x2 ga = pk_fma(nswa, za[k], gca[k]);
            za[k] = pk_fma(scav, ga, za[k]);
            za[k] = __builtin_elementwise_min(__builtin_elementwise_max(za[k], lo), hi);
            f32x2 gb = pk_fma(nswb, zb[k], gcb[k]);
            zb[k] = pk_fma(scbv, gb, zb[k]);
            zb[k] = __builtin_elementwise_min(__builtin_elementwise_max(zb[k], lo), hi);
        }
    }

    float4 oa0 = {za[0].x, za[0].y, za[1].x, za[1].y};
    float4 oa1 = {za[2].x, za[2].y, za[3].x, za[3].y};
    float4 ob0 = {zb[0].x, zb[0].y, zb[1].x, zb[1].y};
    float4 ob1 = {zb[2].x, zb[2].y, zb[3].x, zb[3].y};
    float4* op = (float4*)out;
    op[(size_t)ia * 2]     = oa0;
    op[(size_t)ia * 2 + 1] = oa1;
    op[(size_t)ib * 2]     = ob0;
    op[(size_t)ib * 2 + 1] = ob1;
}

extern "C" void kernel_launch(void* const* d_in, const int* in_sizes, int n_in,
                              void* d_out, int out_size, void* d_ws, size_t ws_size,
                              hipStream_t stream) {
    const float* z       = (const float*)d_in[0];
    const float* centers = (const float*)d_in[1];
    const float* mus     = (const float*)d_in[2];
    float* out           = (float*)d_out;

    dim3 block(256);
    dim3 grid(NB / 2 / 256);   // 1024 blocks, 2 points per thread
    pm_kernel<<<grid, block, 0, stream>>>(z, centers, mus, out);
}